// Round 1
// baseline (914.567 us; speedup 1.0000x reference)
//
#include <hip/hip_runtime.h>
#include <cstdint>

typedef unsigned short u16;
typedef __bf16 bf16x8 __attribute__((ext_vector_type(8)));
typedef float f32x4 __attribute__((ext_vector_type(4)));

// Problem constants
#define B_    16
#define CIN   512
#define COUT  512
#define HW_   64
#define PW    66            // padded width/height
#define XH_ELEMS ((size_t)B_*PW*PW*CIN)              // 35,684,352 u16 (71.4 MB)
#define WA_ELEMS ((size_t)B_*16*9*COUT*32)           // 37,748,736 u16 (75.5 MB)

__device__ __forceinline__ float bf2f(u16 v) {
  union { unsigned int u; float f; } c; c.u = ((unsigned int)v) << 16; return c.f;
}
__device__ __forceinline__ u16 f2bf(float f) {
  union { float f; unsigned int u; } c; c.f = f;
  unsigned int u = c.u + 0x7fffu + ((c.u >> 16) & 1u);   // RNE
  return (u16)(u >> 16);
}

// async global->LDS, 16B per lane; dest must be wave-uniform-base + lane*16
__device__ __forceinline__ void async16(const void* g, void* l) {
  __builtin_amdgcn_global_load_lds(
      (__attribute__((address_space(1))) unsigned int*)(uintptr_t)g,
      (__attribute__((address_space(3))) unsigned int*)(uintptr_t)l,
      16, 0, 0);
}

// ---------------------------------------------------------------------------
// Kernel 1: zero the padding border of xh[b][66][66][512]
__global__ __launch_bounds__(256) void zero_border(u16* __restrict__ xh) {
  int g = blockIdx.x * 256 + threadIdx.x;
  if (g >= B_ * 260 * 64) return;
  int c8 = g & 63;
  int t  = g >> 6;             // 0 .. 16*260-1
  int b  = t / 260;
  int p  = t - b * 260;
  int rp, cp;
  if (p < 66)       { rp = 0;      cp = p; }
  else if (p < 132) { rp = 65;     cp = p - 66; }
  else {
    int q = p - 132;           // 0..127
    if (q < 64) { rp = q + 1;  cp = 0; }
    else        { rp = q - 63; cp = 65; }
  }
  u16* dst = xh + ((((size_t)b * PW + rp) * PW + cp) << 9) + (c8 << 3);
  *(uint4*)dst = make_uint4(0u, 0u, 0u, 0u);
}

// ---------------------------------------------------------------------------
// Kernel 2: fp32 NCHW -> bf16 padded NHWC transpose
__global__ __launch_bounds__(256) void transpose_x(const float* __restrict__ x,
                                                   u16* __restrict__ xh) {
  __shared__ u16 tile[64][72];   // [ci][x], +8 pad
  const int b  = blockIdx.z;
  const int y  = blockIdx.y;
  const int i0 = blockIdx.x * 64;
  const int t  = threadIdx.x;

  const int ciL = t >> 4;            // 0..15
  const int xg  = (t & 15) * 4;      // 0,4,...,60
#pragma unroll
  for (int u = 0; u < 4; ++u) {
    const int ci = ciL + u * 16;
    const float4 v = *(const float4*)(
        x + ((((size_t)b * CIN + i0 + ci) * HW_ + y) * HW_ + xg));
    u16* d = &tile[ci][xg];
    d[0] = f2bf(v.x); d[1] = f2bf(v.y); d[2] = f2bf(v.z); d[3] = f2bf(v.w);
  }
  __syncthreads();

  const int xx = t >> 2;             // 0..63
  const int cg = (t & 3) * 16;       // ci group of 16
  u16 outv[16];
#pragma unroll
  for (int u = 0; u < 16; ++u) outv[u] = tile[cg + u][xx];
  u16* dst = xh + ((((size_t)b * PW + (y + 1)) * PW + (xx + 1)) << 9) + i0 + cg;
  *(uint4*)dst       = *(uint4*)&outv[0];
  *(uint4*)(dst + 8) = *(uint4*)&outv[8];
}

// ---------------------------------------------------------------------------
// Kernel 3: modulate + demodulate weights (fp32 in), write bf16 MFMA layout
// wA[b][ic=i/32][tap][o][i%32] bf16.  One wave per (b,o): 8192 waves.
__global__ __launch_bounds__(256) void mod_weights(const float* __restrict__ w,
                                                   const float* __restrict__ s,
                                                   u16* __restrict__ wA) {
  const int gwid = (blockIdx.x * 256 + threadIdx.x) >> 6;  // 0..8191
  const int lane = threadIdx.x & 63;
  const int b = gwid >> 9;
  const int o = gwid & 511;
  const float* wrow = w + (size_t)o * (CIN * 9);
  const float* srow = s + (size_t)b * CIN;

  float acc = 0.f;
  float sv[8];
#pragma unroll
  for (int j = 0; j < 8; ++j) {
    const int i = lane + j * 64;
    const float si = srow[i];
    sv[j] = si;
    const float* wp = wrow + i * 9;
    float q = 0.f;
#pragma unroll
    for (int t = 0; t < 9; ++t) { float wv = wp[t]; q += wv * wv; }
    acc += si * si * q;
  }
#pragma unroll
  for (int off = 32; off > 0; off >>= 1) acc += __shfl_xor(acc, off, 64);

  const float C_EQ = 1.4731391e-2f;                 // 1/sqrt(512*9)
  const float sigma_inv = rsqrtf(acc * (C_EQ * C_EQ) + 1e-8f);

  u16* base = wA + (size_t)b * (16 * 9 * COUT * 32);
#pragma unroll
  for (int j = 0; j < 8; ++j) {
    const int i = lane + j * 64;
    const float scale = C_EQ * sv[j] * sigma_inv;
    const float* wp = wrow + i * 9;
    const int icc = i >> 5, ich = i & 31;
#pragma unroll
    for (int t = 0; t < 9; ++t) {
      base[(((icc * 9 + t) * COUT) + o) * 32 + ich] = f2bf(wp[t] * scale);
    }
  }
}

// ---------------------------------------------------------------------------
// Kernel 4: implicit-GEMM conv, all-9-taps-resident schedule.
//   Block: 128 o x 8 output rows (512 px), 4 waves, 1 block/CU (116 KB LDS).
//   Wave tile: 128 o x (2 rows x 64 px)  -> acc[8][8] f32x4.
//   Per ic-chunk (32 ch): As[9][128][32] staged once, Bs[10][66][32] staged
//   once, 576 MFMAs per wave between a single barrier pair.  Next chunk's
//   A+B staging is issued after tap-8's fragment preload and hidden under
//   tap-8's 64 MFMAs.
__device__ __forceinline__ void stage_A(const u16* __restrict__ wb,
                                        u16* As, int ic, int o0, int tid) {
  // 73,728 B = 4,608 x 16B chunks = 18 per thread (exact)
#pragma unroll
  for (int t = 0; t < 18; ++t) {
    const int id  = t * 256 + tid;
    const int tap = id >> 9;          // 0..8
    const int rem = id & 511;         // (o_local*4 + k)
    const u16* src = wb + (((size_t)(ic * 9 + tap) * COUT + o0) << 5) + rem * 8;
    async16(src, As + id * 8);
  }
}

__device__ __forceinline__ void stage_B(const u16* __restrict__ xb,
                                        u16* Bs, int ic, int y0, int tid) {
  // 10 rows x 66 cols x 32 ch = 42,240 B = 2,640 chunks = 10/thread + 80
  const u16* src0 = xb + ((size_t)y0 * PW) * CIN + ic * 32;
#pragma unroll
  for (int t = 0; t < 10; ++t) {
    const int id = t * 256 + tid;
    async16(src0 + (size_t)(id >> 2) * CIN + (id & 3) * 8, Bs + id * 8);
  }
  if (tid < 80) {
    const int id = 2560 + tid;
    async16(src0 + (size_t)(id >> 2) * CIN + (id & 3) * 8, Bs + id * 8);
  }
}

__global__ __launch_bounds__(256, 1) void modconv_mfma(const u16* __restrict__ xh,
                                                       const u16* __restrict__ wA,
                                                       const float* __restrict__ bias,
                                                       float* __restrict__ out) {
  __shared__ u16 As[9 * 128 * 32];      // 73,728 B  [tap][o_local][ch]
  __shared__ u16 Bs[10 * 66 * 32];      // 42,240 B  [row][col][ch]

  const int tid  = threadIdx.x;
  const int lane = tid & 63;
  const int wv   = tid >> 6;
  const int l15  = lane & 15;
  const int q    = lane >> 4;           // k-quad 0..3
  const int wrow = wv << 1;             // wave's output-row pair base (0,2,4,6)

  // XCD-aware bijective swizzle: 512 blocks = 8 XCDs x 64.  Consecutive
  // logical ids (y fastest, then o-tile, then b) stay on one XCD so the
  // per-phase A slab + B image slice are L2-resident.
  const int lin     = blockIdx.x;
  const int logical = ((lin & 7) << 6) + (lin >> 3);
  const int yt = logical & 7;
  const int ot = (logical >> 3) & 3;
  const int b  = logical >> 5;
  const int y0 = yt << 3;               // 8 output rows per block
  const int o0 = ot << 7;               // 128 outputs per block

  const u16* xb = xh + (size_t)b * (PW * PW * CIN);
  const u16* wb = wA + (size_t)b * (16 * 9 * COUT * 32);

  f32x4 acc[8][8];                      // [mi][r*4+cg]
#pragma unroll
  for (int mi = 0; mi < 8; ++mi)
#pragma unroll
    for (int n = 0; n < 8; ++n) acc[mi][n] = (f32x4){0.f, 0.f, 0.f, 0.f};

  stage_B(xb, Bs, 0, y0, tid);
  stage_A(wb, As, 0, o0, tid);
  __syncthreads();

  for (int ic = 0; ic < 16; ++ic) {
    // ---- taps 0..7: barrier-free, compiler pipelines ds_read ahead of MFMA
#pragma unroll
    for (int tap = 0; tap < 8; ++tap) {
      const int ky = tap / 3, kx = tap % 3;
      bf16x8 bfr[2][4];
#pragma unroll
      for (int r = 0; r < 2; ++r)
#pragma unroll
        for (int cg = 0; cg < 4; ++cg)
          bfr[r][cg] = *(const bf16x8*)
            &Bs[(((wrow + r + ky) * 66 + cg * 16 + l15 + kx) << 5) + (q << 3)];
#pragma unroll
      for (int mi = 0; mi < 8; ++mi) {
        const bf16x8 af = *(const bf16x8*)
          &As[(((tap << 7) + (mi << 4) + l15) << 5) + (q << 3)];
#pragma unroll
        for (int r = 0; r < 2; ++r)
#pragma unroll
          for (int cg = 0; cg < 4; ++cg)
            acc[mi][r * 4 + cg] = __builtin_amdgcn_mfma_f32_16x16x32_bf16(
                af, bfr[r][cg], acc[mi][r * 4 + cg], 0, 0, 0);
      }
    }

    // ---- tap 8 (ky=2,kx=2): preload ALL its fragments into registers,
    // barrier, then issue next chunk's staging and hide it under the MFMAs.
    bf16x8 bfr8[2][4];
#pragma unroll
    for (int r = 0; r < 2; ++r)
#pragma unroll
      for (int cg = 0; cg < 4; ++cg)
        bfr8[r][cg] = *(const bf16x8*)
          &Bs[(((wrow + r + 2) * 66 + cg * 16 + l15 + 2) << 5) + (q << 3)];
    bf16x8 af8[8];
#pragma unroll
    for (int mi = 0; mi < 8; ++mi)
      af8[mi] = *(const bf16x8*)
        &As[(((8 << 7) + (mi << 4) + l15) << 5) + (q << 3)];

    __syncthreads();                    // all LDS reads of this chunk done
    if (ic < 15) {
      stage_B(xb, Bs, ic + 1, y0, tid); // overwrite: safe, readers drained
      stage_A(wb, As, ic + 1, o0, tid);
    }
#pragma unroll
    for (int mi = 0; mi < 8; ++mi)
#pragma unroll
      for (int r = 0; r < 2; ++r)
#pragma unroll
        for (int cg = 0; cg < 4; ++cg)
          acc[mi][r * 4 + cg] = __builtin_amdgcn_mfma_f32_16x16x32_bf16(
              af8[mi], bfr8[r][cg], acc[mi][r * 4 + cg], 0, 0, 0);
    __syncthreads();                    // drains vmcnt(0): staged data visible
  }

  // epilogue: D mapping col = lane&15 (pixel), row = q*4+reg (o); fp32 out
#pragma unroll
  for (int mi = 0; mi < 8; ++mi) {
#pragma unroll
    for (int rg = 0; rg < 4; ++rg) {
      const int o = o0 + (mi << 4) + (q << 2) + rg;
      const float bv = bias[o];
#pragma unroll
      for (int r = 0; r < 2; ++r) {
        const int y = y0 + wrow + r;
        const size_t base = (((size_t)b * COUT + o) * HW_ + y) * HW_;
#pragma unroll
        for (int cg = 0; cg < 4; ++cg)
          out[base + (cg << 4) + l15] = acc[mi][r * 4 + cg][rg] + bv;
      }
    }
  }
}

// ---------------------------------------------------------------------------
extern "C" void kernel_launch(void* const* d_in, const int* in_sizes, int n_in,
                              void* d_out, int out_size, void* d_ws, size_t ws_size,
                              hipStream_t stream) {
  const float* x    = (const float*)d_in[0];   // [16][512][64][64] fp32
  const float* s    = (const float*)d_in[1];   // [16][512] fp32
  const float* w    = (const float*)d_in[2];   // [512][512][3][3] fp32
  const float* bias = (const float*)d_in[3];   // [512] fp32
  float* out = (float*)d_out;                  // [16][512][64][64] fp32

  u16* xh = (u16*)d_ws;                        // padded NHWC bf16 input
  u16* wA = xh + XH_ELEMS;                     // modulated bf16 weights

  zero_border<<<(B_ * 260 * 64 + 255) / 256, 256, 0, stream>>>(xh);
  transpose_x<<<dim3(8, 64, 16), 256, 0, stream>>>(x, xh);
  mod_weights<<<2048, 256, 0, stream>>>(w, s, wA);
  modconv_mfma<<<512, 256, 0, stream>>>(xh, wA, bias, out);
}

// Round 2
// 529.500 us; speedup vs baseline: 1.7272x; 1.7272x over previous
//
#include <hip/hip_runtime.h>
#include <cstdint>

typedef unsigned short u16;
typedef __bf16 bf16x8 __attribute__((ext_vector_type(8)));
typedef float f32x4 __attribute__((ext_vector_type(4)));

// Problem constants
#define B_    16
#define CIN   512
#define COUT  512
#define HW_   64
#define PW    66            // padded width/height
#define XH_ELEMS ((size_t)B_*PW*PW*CIN)              // 35,684,352 u16 (71.4 MB)
#define WA_ELEMS ((size_t)B_*16*9*COUT*32)           // 37,748,736 u16 (75.5 MB)

__device__ __forceinline__ float bf2f(u16 v) {
  union { unsigned int u; float f; } c; c.u = ((unsigned int)v) << 16; return c.f;
}
__device__ __forceinline__ u16 f2bf(float f) {
  union { float f; unsigned int u; } c; c.f = f;
  unsigned int u = c.u + 0x7fffu + ((c.u >> 16) & 1u);   // RNE
  return (u16)(u >> 16);
}

// async global->LDS, 16B per lane; dest must be wave-uniform-base + lane*16
__device__ __forceinline__ void async16(const void* g, void* l) {
  __builtin_amdgcn_global_load_lds(
      (__attribute__((address_space(1))) unsigned int*)(uintptr_t)g,
      (__attribute__((address_space(3))) unsigned int*)(uintptr_t)l,
      16, 0, 0);
}

// ---------------------------------------------------------------------------
// Kernel 1: zero the padding border of xh[b][66][66][512]
__global__ __launch_bounds__(256) void zero_border(u16* __restrict__ xh) {
  int g = blockIdx.x * 256 + threadIdx.x;
  if (g >= B_ * 260 * 64) return;
  int c8 = g & 63;
  int t  = g >> 6;             // 0 .. 16*260-1
  int b  = t / 260;
  int p  = t - b * 260;
  int rp, cp;
  if (p < 66)       { rp = 0;      cp = p; }
  else if (p < 132) { rp = 65;     cp = p - 66; }
  else {
    int q = p - 132;           // 0..127
    if (q < 64) { rp = q + 1;  cp = 0; }
    else        { rp = q - 63; cp = 65; }
  }
  u16* dst = xh + ((((size_t)b * PW + rp) * PW + cp) << 9) + (c8 << 3);
  *(uint4*)dst = make_uint4(0u, 0u, 0u, 0u);
}

// ---------------------------------------------------------------------------
// Kernel 2: fp32 NCHW -> bf16 padded NHWC transpose
__global__ __launch_bounds__(256) void transpose_x(const float* __restrict__ x,
                                                   u16* __restrict__ xh) {
  __shared__ u16 tile[64][72];   // [ci][x], +8 pad
  const int b  = blockIdx.z;
  const int y  = blockIdx.y;
  const int i0 = blockIdx.x * 64;
  const int t  = threadIdx.x;

  const int ciL = t >> 4;            // 0..15
  const int xg  = (t & 15) * 4;      // 0,4,...,60
#pragma unroll
  for (int u = 0; u < 4; ++u) {
    const int ci = ciL + u * 16;
    const float4 v = *(const float4*)(
        x + ((((size_t)b * CIN + i0 + ci) * HW_ + y) * HW_ + xg));
    u16* d = &tile[ci][xg];
    d[0] = f2bf(v.x); d[1] = f2bf(v.y); d[2] = f2bf(v.z); d[3] = f2bf(v.w);
  }
  __syncthreads();

  const int xx = t >> 2;             // 0..63
  const int cg = (t & 3) * 16;       // ci group of 16
  u16 outv[16];
#pragma unroll
  for (int u = 0; u < 16; ++u) outv[u] = tile[cg + u][xx];
  u16* dst = xh + ((((size_t)b * PW + (y + 1)) * PW + (xx + 1)) << 9) + i0 + cg;
  *(uint4*)dst       = *(uint4*)&outv[0];
  *(uint4*)(dst + 8) = *(uint4*)&outv[8];
}

// ---------------------------------------------------------------------------
// Kernel 3: modulate + demodulate weights (fp32 in), write bf16 MFMA layout
// wA[b][ic=i/32][tap][o][i%32] bf16.  One wave per (b,o): 8192 waves.
__global__ __launch_bounds__(256) void mod_weights(const float* __restrict__ w,
                                                   const float* __restrict__ s,
                                                   u16* __restrict__ wA) {
  const int gwid = (blockIdx.x * 256 + threadIdx.x) >> 6;  // 0..8191
  const int lane = threadIdx.x & 63;
  const int b = gwid >> 9;
  const int o = gwid & 511;
  const float* wrow = w + (size_t)o * (CIN * 9);
  const float* srow = s + (size_t)b * CIN;

  float acc = 0.f;
  float sv[8];
#pragma unroll
  for (int j = 0; j < 8; ++j) {
    const int i = lane + j * 64;
    const float si = srow[i];
    sv[j] = si;
    const float* wp = wrow + i * 9;
    float q = 0.f;
#pragma unroll
    for (int t = 0; t < 9; ++t) { float wv = wp[t]; q += wv * wv; }
    acc += si * si * q;
  }
#pragma unroll
  for (int off = 32; off > 0; off >>= 1) acc += __shfl_xor(acc, off, 64);

  const float C_EQ = 1.4731391e-2f;                 // 1/sqrt(512*9)
  const float sigma_inv = rsqrtf(acc * (C_EQ * C_EQ) + 1e-8f);

  u16* base = wA + (size_t)b * (16 * 9 * COUT * 32);
#pragma unroll
  for (int j = 0; j < 8; ++j) {
    const int i = lane + j * 64;
    const float scale = C_EQ * sv[j] * sigma_inv;
    const float* wp = wrow + i * 9;
    const int icc = i >> 5, ich = i & 31;
#pragma unroll
    for (int t = 0; t < 9; ++t) {
      base[(((icc * 9 + t) * COUT) + o) * 32 + ich] = f2bf(wp[t] * scale);
    }
  }
}

// ---------------------------------------------------------------------------
// Kernel 4: implicit-GEMM conv, swizzled LDS + 1-barrier-per-tap pipeline.
//   Block: 128 o x 256 px (4 output rows), 4 waves.
//   Wave tile: 128 o x 64 px (1 row)  -> acc[8][4] = 128 VGPR.
//   A (weights, per-tap 128x32) double-buffered, staged 1 phase ahead.
//   B (input window 6 rows x 66 x 32ch) double-buffered per ic-chunk,
//   staged in 8 slices spread over taps 0..7 of the previous chunk.
//   LDS 67 KB -> 2 blocks/CU.  XOR bank-swizzle (slot ^= row&3) applied as
//   inverse-permuted GLOBAL source + swizzled ds_read (rule: both sides).
#define AS_ELEMS (128 * 32)            // 4096 u16 per A buffer (8 KB)
#define BROWS    (6 * 66)              // 396 rows per B buffer
#define BS_ELEMS (BROWS * 32)          // 12672 u16 per B buffer (25.3 KB)

__device__ __forceinline__ void stage_A(const u16* __restrict__ wb,
                                        u16* dst, int phase, int o0, int tid) {
  // 8 KB = 512 x 16B chunks, 2/thread.  LDS chunk id holds global chunk
  // (row, slot^(row&3)) so a swizzled read returns the natural layout.
  const u16* asrc = wb + ((size_t)phase * COUT + o0) * 32;
#pragma unroll
  for (int t = 0; t < 2; ++t) {
    const int id   = t * 256 + tid;
    const int row  = id >> 2;
    const int slot = (id & 3) ^ (row & 3);
    async16(asrc + row * 32 + slot * 8, dst + id * 8);
  }
}

__device__ __forceinline__ void stage_B_slice(const u16* __restrict__ xb,
                                              u16* dst, int ic, int y0,
                                              int tid, int slice) {
  // 25.3 KB = 1584 chunks = 8 slices x 198
  if (tid < 198) {
    const int id   = slice * 198 + tid;
    const int row  = id >> 2;                  // rr*66+cc pixel in window
    const int slot = (id & 3) ^ (row & 3);
    async16(xb + ((size_t)y0 * PW + row) * CIN + ic * 32 + slot * 8,
            dst + id * 8);
  }
}

__global__ __launch_bounds__(256, 2) void modconv_mfma(const u16* __restrict__ xh,
                                                       const u16* __restrict__ wA,
                                                       const float* __restrict__ bias,
                                                       float* __restrict__ out) {
  __shared__ u16 As[2 * AS_ELEMS];     // 16 KB   [buf][o_local][ch]
  __shared__ u16 Bs[2 * BS_ELEMS];     // 50.7 KB [buf][row][ch]

  const int tid  = threadIdx.x;
  const int lane = tid & 63;
  const int wv   = tid >> 6;           // wave's output row within 4-row tile
  const int l15  = lane & 15;
  const int q    = lane >> 4;          // k-quad 0..3
  const int sw15 = l15 & 3;            // row&3 contribution from l15

  // XCD-aware bijective swizzle: 1024 blocks = 8 XCDs x 128.
  const int lin     = blockIdx.x;
  const int logical = ((lin & 7) << 7) + (lin >> 3);
  const int yt = logical & 15;
  const int ot = (logical >> 4) & 3;
  const int b  = logical >> 6;
  const int y0 = yt << 2;              // 4 output rows per block
  const int o0 = ot << 7;              // 128 outputs per block

  const u16* xb = xh + (size_t)b * (PW * PW * CIN);
  const u16* wb = wA + (size_t)b * (16 * 9 * COUT * 32);

  f32x4 acc[8][4];                     // [mi over 128 o][cg over 64 px]
#pragma unroll
  for (int mi = 0; mi < 8; ++mi)
#pragma unroll
    for (int cg = 0; cg < 4; ++cg) acc[mi][cg] = (f32x4){0.f, 0.f, 0.f, 0.f};

  // prologue: B chunk 0 (all 8 slices) + A phase 0
#pragma unroll
  for (int s = 0; s < 8; ++s) stage_B_slice(xb, Bs, 0, y0, tid, s);
  stage_A(wb, As, 0, o0, tid);

  for (int ic = 0; ic < 16; ++ic) {
    const int icp   = ic & 1;
    const int bOff  = icp * BS_ELEMS;
    const int bOffN = BS_ELEMS - bOff;
#pragma unroll
    for (int tap = 0; tap < 9; ++tap) {
      // one barrier per phase: staged data from previous phase now visible
      // (syncthreads drains vmcnt), and all reads of the other buffers done.
      __syncthreads();

      const int aCur = (((ic + tap) & 1) ? AS_ELEMS : 0);
      const int aNxt = AS_ELEMS - aCur;
      if (!(ic == 15 && tap == 8))
        stage_A(wb, As + aNxt, ic * 9 + tap + 1, o0, tid);
      if (ic < 15 && tap < 8)
        stage_B_slice(xb, Bs + bOffN, ic + 1, y0, tid, tap);

      const int ky = tap / 3, kx = tap % 3;
      const int rbbase = (wv + ky) * 66 + kx;        // B row base for this wave

      bf16x8 bfr[4];
#pragma unroll
      for (int cg = 0; cg < 4; ++cg) {
        const int rb = rbbase + cg * 16 + l15;
        bfr[cg] = *(const bf16x8*)
          &Bs[bOff + (rb << 5) + ((q ^ (rb & 3)) << 3)];
      }

      __builtin_amdgcn_s_setprio(1);
#pragma unroll
      for (int mi = 0; mi < 8; ++mi) {
        const int ra = (mi << 4) + l15;
        const bf16x8 af = *(const bf16x8*)
          &As[aCur + (ra << 5) + ((q ^ sw15) << 3)];
#pragma unroll
        for (int cg = 0; cg < 4; ++cg)
          acc[mi][cg] = __builtin_amdgcn_mfma_f32_16x16x32_bf16(
              af, bfr[cg], acc[mi][cg], 0, 0, 0);
      }
      __builtin_amdgcn_s_setprio(0);
    }
  }

  // epilogue: D col = l15 (pixel), row = q*4+reg (o); fp32 out + bias
  const int y = y0 + wv;
#pragma unroll
  for (int mi = 0; mi < 8; ++mi) {
#pragma unroll
    for (int rg = 0; rg < 4; ++rg) {
      const int o = o0 + (mi << 4) + (q << 2) + rg;
      const float bv = bias[o];
      const size_t base = (((size_t)b * COUT + o) * HW_ + y) * HW_;
#pragma unroll
      for (int cg = 0; cg < 4; ++cg)
        out[base + (cg << 4) + l15] = acc[mi][cg][rg] + bv;
    }
  }
}

// ---------------------------------------------------------------------------
extern "C" void kernel_launch(void* const* d_in, const int* in_sizes, int n_in,
                              void* d_out, int out_size, void* d_ws, size_t ws_size,
                              hipStream_t stream) {
  const float* x    = (const float*)d_in[0];   // [16][512][64][64] fp32
  const float* s    = (const float*)d_in[1];   // [16][512] fp32
  const float* w    = (const float*)d_in[2];   // [512][512][3][3] fp32
  const float* bias = (const float*)d_in[3];   // [512] fp32
  float* out = (float*)d_out;                  // [16][512][64][64] fp32

  u16* xh = (u16*)d_ws;                        // padded NHWC bf16 input
  u16* wA = xh + XH_ELEMS;                     // modulated bf16 weights

  zero_border<<<(B_ * 260 * 64 + 255) / 256, 256, 0, stream>>>(xh);
  transpose_x<<<dim3(8, 64, 16), 256, 0, stream>>>(x, xh);
  mod_weights<<<2048, 256, 0, stream>>>(w, s, wA);
  modconv_mfma<<<1024, 256, 0, stream>>>(xh, wA, bias, out);
}

// Round 3
// 484.386 us; speedup vs baseline: 1.8881x; 1.0931x over previous
//
#include <hip/hip_runtime.h>
#include <cstdint>

typedef unsigned short u16;
typedef __bf16 bf16x8 __attribute__((ext_vector_type(8)));
typedef float f32x4 __attribute__((ext_vector_type(4)));

// Problem constants
#define B_    16
#define CIN   512
#define COUT  512
#define HW_   64
#define PW    66            // padded width/height
#define XH_ELEMS ((size_t)B_*PW*PW*CIN)              // 35,684,352 u16 (71.4 MB)
#define WA_ELEMS ((size_t)B_*16*9*COUT*32)           // 37,748,736 u16 (75.5 MB)

#define WAITV(N) asm volatile("s_waitcnt vmcnt(" #N ")" ::: "memory")

__device__ __forceinline__ u16 f2bf(float f) {
  union { float f; unsigned int u; } c; c.f = f;
  unsigned int u = c.u + 0x7fffu + ((c.u >> 16) & 1u);   // RNE
  return (u16)(u >> 16);
}

// async global->LDS, 16B per lane; dest must be wave-uniform-base + lane*16
__device__ __forceinline__ void async16(const void* g, void* l) {
  __builtin_amdgcn_global_load_lds(
      (__attribute__((address_space(1))) unsigned int*)(uintptr_t)g,
      (__attribute__((address_space(3))) unsigned int*)(uintptr_t)l,
      16, 0, 0);
}

// ---------------------------------------------------------------------------
// Kernel 1: zero the padding border of xh[b][66][66][512]
__global__ __launch_bounds__(256) void zero_border(u16* __restrict__ xh) {
  int g = blockIdx.x * 256 + threadIdx.x;
  if (g >= B_ * 260 * 64) return;
  int c8 = g & 63;
  int t  = g >> 6;             // 0 .. 16*260-1
  int b  = t / 260;
  int p  = t - b * 260;
  int rp, cp;
  if (p < 66)       { rp = 0;      cp = p; }
  else if (p < 132) { rp = 65;     cp = p - 66; }
  else {
    int q = p - 132;           // 0..127
    if (q < 64) { rp = q + 1;  cp = 0; }
    else        { rp = q - 63; cp = 65; }
  }
  u16* dst = xh + ((((size_t)b * PW + rp) * PW + cp) << 9) + (c8 << 3);
  *(uint4*)dst = make_uint4(0u, 0u, 0u, 0u);
}

// ---------------------------------------------------------------------------
// Kernel 2: fp32 NCHW -> bf16 padded NHWC transpose
__global__ __launch_bounds__(256) void transpose_x(const float* __restrict__ x,
                                                   u16* __restrict__ xh) {
  __shared__ u16 tile[64][72];   // [ci][x], +8 pad
  const int b  = blockIdx.z;
  const int y  = blockIdx.y;
  const int i0 = blockIdx.x * 64;
  const int t  = threadIdx.x;

  const int ciL = t >> 4;            // 0..15
  const int xg  = (t & 15) * 4;      // 0,4,...,60
#pragma unroll
  for (int u = 0; u < 4; ++u) {
    const int ci = ciL + u * 16;
    const float4 v = *(const float4*)(
        x + ((((size_t)b * CIN + i0 + ci) * HW_ + y) * HW_ + xg));
    u16* d = &tile[ci][xg];
    d[0] = f2bf(v.x); d[1] = f2bf(v.y); d[2] = f2bf(v.z); d[3] = f2bf(v.w);
  }
  __syncthreads();

  const int xx = t >> 2;             // 0..63
  const int cg = (t & 3) * 16;       // ci group of 16
  u16 outv[16];
#pragma unroll
  for (int u = 0; u < 16; ++u) outv[u] = tile[cg + u][xx];
  u16* dst = xh + ((((size_t)b * PW + (y + 1)) * PW + (xx + 1)) << 9) + i0 + cg;
  *(uint4*)dst       = *(uint4*)&outv[0];
  *(uint4*)(dst + 8) = *(uint4*)&outv[8];
}

// ---------------------------------------------------------------------------
// Kernel 3a: demod sigma.  One wave per o; all 16 batches reduced in-wave.
// sig[b][o] = rsqrt(C^2 * sum_i s[b][i]^2 * sum_t w[o][i][t]^2 + eps).
// Output parked in d_out scratch (conv fully overwrites it later).
__global__ __launch_bounds__(256) void sigma_kernel(const float* __restrict__ w,
                                                    const float* __restrict__ s,
                                                    float* __restrict__ sig) {
  const int o    = blockIdx.x * 4 + (threadIdx.x >> 6);
  const int lane = threadIdx.x & 63;
  const float* wrow = w + (size_t)o * (CIN * 9);

  float q[8];
#pragma unroll
  for (int j = 0; j < 8; ++j) {
    const float* wp = wrow + (lane + j * 64) * 9;
    float qq = 0.f;
#pragma unroll
    for (int t = 0; t < 9; ++t) { const float wv = wp[t]; qq += wv * wv; }
    q[j] = qq;
  }
  const float C_EQ = 1.4731391e-2f;                 // 1/sqrt(512*9)
#pragma unroll
  for (int b = 0; b < 16; ++b) {
    const float* srow = s + (size_t)b * CIN;
    float acc = 0.f;
#pragma unroll
    for (int j = 0; j < 8; ++j) {
      const float si = srow[lane + j * 64];
      acc += si * si * q[j];
    }
#pragma unroll
    for (int off = 32; off > 0; off >>= 1) acc += __shfl_xor(acc, off, 64);
    if (lane == 0) sig[b * COUT + o] = rsqrtf(acc * (C_EQ * C_EQ) + 1e-8f);
  }
}

// ---------------------------------------------------------------------------
// Kernel 3b: scale + layout weights.  Block = (b, icc, o-quarter of 64).
// Reads w slab coalesced (float4), LDS transpose, writes wA coalesced (uint4).
// wA[b][icc][tap][o][ich] bf16, same layout the conv consumes.
__global__ __launch_bounds__(256, 2) void scale_weights(const float* __restrict__ w,
                                                        const float* __restrict__ s,
                                                        const float* __restrict__ sig,
                                                        u16* __restrict__ wA) {
  __shared__ float wld[64 * 292];    // 74,752 B  [o_local][i_local*9+tap]
  __shared__ float s2[32];
  __shared__ float si[64];

  const int tid = threadIdx.x;
  // XCD swizzle: 2048 = 8 x 256.  XCD k gets oq == k entirely -> each XCD
  // re-reads only its own 64-o slice of w (1.18 MB, L2-resident).
  const int lin = blockIdx.x;
  const int l   = ((lin & 7) << 8) + (lin >> 3);
  const int b   = l & 15;
  const int sid = l >> 4;            // 0..127
  const int icc = sid & 15;
  const int oq  = sid >> 4;          // 0..7
  const int o0  = oq << 6;

  // load w slab: 64 o x 288 floats (i-chunk of 32 x 9 taps), float4-coalesced
#pragma unroll
  for (int k = 0; k < 18; ++k) {
    const int c   = k * 256 + tid;       // 0..4607
    const int ol  = c / 72;
    const int col = c - ol * 72;
    const float4 v = *(const float4*)(
        w + ((size_t)(o0 + ol) * 512 + icc * 32) * 9 + col * 4);
    *(float4*)&wld[ol * 292 + col * 4] = v;
  }
  if (tid < 32) s2[tid] = 1.4731391e-2f * s[(size_t)b * CIN + icc * 32 + tid];
  else if (tid < 96) si[tid - 32] = sig[(size_t)b * COUT + o0 + (tid - 32)];
  __syncthreads();

  u16* base = wA + (size_t)b * (16 * 9 * COUT * 32);
#pragma unroll
  for (int tap = 0; tap < 9; ++tap) {
    const int ol = tid >> 2;
    const int g  = tid & 3;
    const float sg = si[ol];
    u16 outc[8];
#pragma unroll
    for (int kk = 0; kk < 8; ++kk) {
      const int i = g * 8 + kk;
      outc[kk] = f2bf(wld[ol * 292 + i * 9 + tap] * s2[i] * sg);
    }
    *(uint4*)(base + (((size_t)(icc * 9 + tap) * COUT) + o0 + ol) * 32 + g * 8)
        = *(uint4*)outc;
  }
}

// ---------------------------------------------------------------------------
// Kernel 4: implicit-GEMM conv, counted-vmcnt pipeline (T4).
//   Block: 128 o x 256 px (4 output rows), 4 waves; wave: 128 o x 64 px.
//   A triple-buffered (24 KB), staged 2 phases ahead; B (6x66x32 window)
//   double-buffered per ic-chunk, staged in 8 slices over taps 0..7.
//   Raw s_barrier + s_waitcnt vmcnt(N): staging loads stay in flight across
//   barriers with a full phase (~2500 cyc) of slack.  Never vmcnt(0) in the
//   main loop.  Buffer safety: every stage targets a buffer whose readers
//   all passed the barrier the stage is issued after.
#define AS_ELEMS (128 * 32)            // 4096 u16 per A buffer (8 KB)
#define BROWS    (6 * 66)              // 396 rows per B buffer
#define BS_ELEMS (BROWS * 32)          // 12672 u16 per B buffer (25.3 KB)

__device__ __forceinline__ void stage_A(const u16* __restrict__ wb,
                                        u16* dst, int phase, int o0, int tid) {
  // 8 KB = 512 x 16B chunks, 2/thread.  XOR bank-swizzle via global source.
  const u16* asrc = wb + ((size_t)phase * COUT + o0) * 32;
#pragma unroll
  for (int t = 0; t < 2; ++t) {
    const int id   = t * 256 + tid;
    const int row  = id >> 2;
    const int slot = (id & 3) ^ (row & 3);
    async16(asrc + row * 32 + slot * 8, dst + id * 8);
  }
}

__device__ __forceinline__ void stage_B_slice(const u16* __restrict__ xb,
                                              u16* dst, int ic, int y0,
                                              int tid, int slice) {
  // 25.3 KB = 1584 chunks = 8 slices x 198 (uniform 1 instr per wave)
  if (tid < 198) {
    const int id   = slice * 198 + tid;
    const int row  = id >> 2;                  // rr*66+cc pixel in window
    const int slot = (id & 3) ^ (row & 3);
    async16(xb + ((size_t)y0 * PW + row) * CIN + ic * 32 + slot * 8,
            dst + id * 8);
  }
}

__global__ __launch_bounds__(256, 2) void modconv_mfma(const u16* __restrict__ xh,
                                                       const u16* __restrict__ wA,
                                                       const float* __restrict__ bias,
                                                       float* __restrict__ out) {
  __shared__ u16 As[3 * AS_ELEMS];     // 24 KB   [buf][o_local][ch]
  __shared__ u16 Bs[2 * BS_ELEMS];     // 50.7 KB [buf][row][ch]

  const int tid  = threadIdx.x;
  const int lane = tid & 63;
  const int wv   = tid >> 6;           // wave's output row within 4-row tile
  const int l15  = lane & 15;
  const int q    = lane >> 4;          // k-quad 0..3
  const int sw15 = l15 & 3;

  // XCD-aware bijective swizzle: 1024 blocks = 8 XCDs x 128.
  const int lin     = blockIdx.x;
  const int logical = ((lin & 7) << 7) + (lin >> 3);
  const int yt = logical & 15;
  const int ot = (logical >> 4) & 3;
  const int b  = logical >> 6;
  const int y0 = yt << 2;              // 4 output rows per block
  const int o0 = ot << 7;              // 128 outputs per block

  const u16* xb = xh + (size_t)b * (PW * PW * CIN);
  const u16* wb = wA + (size_t)b * (16 * 9 * COUT * 32);

  f32x4 acc[8][4];
#pragma unroll
  for (int mi = 0; mi < 8; ++mi)
#pragma unroll
    for (int cg = 0; cg < 4; ++cg) acc[mi][cg] = (f32x4){0.f, 0.f, 0.f, 0.f};

  // prologue: B chunk 0 (8 slices) then A(0)->buf0, A(1)->buf1.
  // In flight at phase 0 entry: 8 + 2 + 2; vmcnt(2) leaves only A(1) flying.
#pragma unroll
  for (int sl = 0; sl < 8; ++sl) stage_B_slice(xb, Bs, 0, y0, tid, sl);
  stage_A(wb, As, 0, o0, tid);
  stage_A(wb, As + AS_ELEMS, 1, o0, tid);

  // ---- main: ic = 0..14 (full staging every phase) ----
  for (int ic = 0; ic < 15; ++ic) {
    const int bOff = (ic & 1) * BS_ELEMS;
    const int bNxt = BS_ELEMS - bOff;
#pragma unroll
    for (int tap = 0; tap < 9; ++tap) {
      // entry wait: prev phase issued 2 (tap8: A only) or 3 (A+B) loads.
      // Waiting to N leaves exactly prev phase's loads in flight ->
      // everything older (this phase's A buf, B slices) has landed.
      if (tap == 0) { WAITV(2); } else { WAITV(3); }
      __builtin_amdgcn_s_barrier();
      __builtin_amdgcn_sched_barrier(0);

      const int ky = tap / 3, kx = tap % 3;
      const int aCur = (tap % 3) * AS_ELEMS;        // g%3 == tap%3 (9%3==0)
      const int aDst = ((tap + 2) % 3) * AS_ELEMS;
      const int rbbase = (wv + ky) * 66 + kx;

      bf16x8 bfr[4];
#pragma unroll
      for (int cg = 0; cg < 4; ++cg) {
        const int rb = rbbase + cg * 16 + l15;
        bfr[cg] = *(const bf16x8*)
          &Bs[bOff + (rb << 5) + ((q ^ (rb & 3)) << 3)];
      }

      // staging for phase g+2 (A) and next chunk (B slice = tap)
      stage_A(wb, As + aDst, ic * 9 + tap + 2, o0, tid);
      if (tap < 8) stage_B_slice(xb, Bs + bNxt, ic + 1, y0, tid, tap);

      __builtin_amdgcn_s_setprio(1);
#pragma unroll
      for (int mi = 0; mi < 8; ++mi) {
        const int ra = (mi << 4) + l15;
        const bf16x8 af = *(const bf16x8*)
          &As[aCur + (ra << 5) + ((q ^ sw15) << 3)];
#pragma unroll
        for (int cg = 0; cg < 4; ++cg)
          acc[mi][cg] = __builtin_amdgcn_mfma_f32_16x16x32_bf16(
              af, bfr[cg], acc[mi][cg], 0, 0, 0);
      }
      __builtin_amdgcn_s_setprio(0);
    }
  }

  // ---- tail: ic = 15 (A staged for taps<=6 only, no B staging) ----
  {
    const int bOff = BS_ELEMS;         // ic=15 is odd
#pragma unroll
    for (int tap = 0; tap < 9; ++tap) {
      if (tap < 8) { WAITV(2); } else { WAITV(0); }
      __builtin_amdgcn_s_barrier();
      __builtin_amdgcn_sched_barrier(0);

      const int ky = tap / 3, kx = tap % 3;
      const int aCur = (tap % 3) * AS_ELEMS;
      const int rbbase = (wv + ky) * 66 + kx;

      bf16x8 bfr[4];
#pragma unroll
      for (int cg = 0; cg < 4; ++cg) {
        const int rb = rbbase + cg * 16 + l15;
        bfr[cg] = *(const bf16x8*)
          &Bs[bOff + (rb << 5) + ((q ^ (rb & 3)) << 3)];
      }

      if (tap <= 6)
        stage_A(wb, As + ((tap + 2) % 3) * AS_ELEMS, 135 + tap + 2, o0, tid);

      __builtin_amdgcn_s_setprio(1);
#pragma unroll
      for (int mi = 0; mi < 8; ++mi) {
        const int ra = (mi << 4) + l15;
        const bf16x8 af = *(const bf16x8*)
          &As[aCur + (ra << 5) + ((q ^ sw15) << 3)];
#pragma unroll
        for (int cg = 0; cg < 4; ++cg)
          acc[mi][cg] = __builtin_amdgcn_mfma_f32_16x16x32_bf16(
              af, bfr[cg], acc[mi][cg], 0, 0, 0);
      }
      __builtin_amdgcn_s_setprio(0);
    }
  }

  // epilogue: D col = l15 (pixel), row = q*4+reg (o); fp32 out + bias
  const int y = y0 + wv;
#pragma unroll
  for (int mi = 0; mi < 8; ++mi) {
#pragma unroll
    for (int rg = 0; rg < 4; ++rg) {
      const int o = o0 + (mi << 4) + (q << 2) + rg;
      const float bv = bias[o];
      const size_t base = (((size_t)b * COUT + o) * HW_ + y) * HW_;
#pragma unroll
      for (int cg = 0; cg < 4; ++cg)
        out[base + (cg << 4) + l15] = acc[mi][cg][rg] + bv;
    }
  }
}

// ---------------------------------------------------------------------------
extern "C" void kernel_launch(void* const* d_in, const int* in_sizes, int n_in,
                              void* d_out, int out_size, void* d_ws, size_t ws_size,
                              hipStream_t stream) {
  const float* x    = (const float*)d_in[0];   // [16][512][64][64] fp32
  const float* s    = (const float*)d_in[1];   // [16][512] fp32
  const float* w    = (const float*)d_in[2];   // [512][512][3][3] fp32
  const float* bias = (const float*)d_in[3];   // [512] fp32
  float* out = (float*)d_out;                  // [16][512][64][64] fp32

  u16* xh = (u16*)d_ws;                        // padded NHWC bf16 input
  u16* wA = xh + XH_ELEMS;                     // modulated bf16 weights
  float* sig = (float*)d_out;                  // 32 KB scratch, conv overwrites

  zero_border<<<(B_ * 260 * 64 + 255) / 256, 256, 0, stream>>>(xh);
  transpose_x<<<dim3(8, 64, 16), 256, 0, stream>>>(x, xh);
  sigma_kernel<<<128, 256, 0, stream>>>(w, s, sig);
  scale_weights<<<2048, 256, 0, stream>>>(w, s, sig, wA);
  modconv_mfma<<<1024, 256, 0, stream>>>(xh, wA, bias, out);
}

// Round 4
// 477.210 us; speedup vs baseline: 1.9165x; 1.0150x over previous
//
#include <hip/hip_runtime.h>
#include <cstdint>

typedef unsigned short u16;
typedef __bf16 bf16x8 __attribute__((ext_vector_type(8)));
typedef float f32x4 __attribute__((ext_vector_type(4)));

// Problem constants
#define B_    16
#define CIN   512
#define COUT  512
#define HW_   64
#define PW    66            // padded width/height
#define XH_ELEMS ((size_t)B_*PW*PW*CIN)              // 35,684,352 u16 (71.4 MB)
#define WA_ELEMS ((size_t)B_*16*9*COUT*32)           // 37,748,736 u16 (75.5 MB)

#define WAITV(N) asm volatile("s_waitcnt vmcnt(" #N ")" ::: "memory")

__device__ __forceinline__ u16 f2bf(float f) {
  union { float f; unsigned int u; } c; c.f = f;
  unsigned int u = c.u + 0x7fffu + ((c.u >> 16) & 1u);   // RNE
  return (u16)(u >> 16);
}

// async global->LDS, 16B per lane; dest must be wave-uniform-base + lane*16
__device__ __forceinline__ void async16(const void* g, void* l) {
  __builtin_amdgcn_global_load_lds(
      (__attribute__((address_space(1))) unsigned int*)(uintptr_t)g,
      (__attribute__((address_space(3))) unsigned int*)(uintptr_t)l,
      16, 0, 0);
}

// ---------------------------------------------------------------------------
// Kernel 1: zero the padding border of xh[b][66][66][512]
__global__ __launch_bounds__(256) void zero_border(u16* __restrict__ xh) {
  int g = blockIdx.x * 256 + threadIdx.x;
  if (g >= B_ * 260 * 64) return;
  int c8 = g & 63;
  int t  = g >> 6;             // 0 .. 16*260-1
  int b  = t / 260;
  int p  = t - b * 260;
  int rp, cp;
  if (p < 66)       { rp = 0;      cp = p; }
  else if (p < 132) { rp = 65;     cp = p - 66; }
  else {
    int q = p - 132;           // 0..127
    if (q < 64) { rp = q + 1;  cp = 0; }
    else        { rp = q - 63; cp = 65; }
  }
  u16* dst = xh + ((((size_t)b * PW + rp) * PW + cp) << 9) + (c8 << 3);
  *(uint4*)dst = make_uint4(0u, 0u, 0u, 0u);
}

// ---------------------------------------------------------------------------
// Kernel 2: fp32 NCHW -> bf16 padded NHWC transpose.  ZERO LDS version.
// Block = (i-chunk of 64, y-pair, b).  Thread (c8, xq, y01):
//   loads 8 float4 along x (per-instr lanes: 8 chunks x 128 B contiguous),
//   register-transposes 8ci x 4x, stores 4 uint4 (lanes: 128 B contiguous).
__global__ __launch_bounds__(256) void transpose_x(const float* __restrict__ x,
                                                   u16* __restrict__ xh) {
  const int t   = threadIdx.x;
  const int c8  = t & 7;             // 8-channel group
  const int xq  = (t >> 3) & 15;     // x quad
  const int y01 = t >> 7;            // row within pair
  const int i0  = blockIdx.x * 64;
  const int y   = blockIdx.y * 2 + y01;
  const int b   = blockIdx.z;

  float4 v[8];
#pragma unroll
  for (int k = 0; k < 8; ++k) {
    const int ci = i0 + c8 * 8 + k;
    v[k] = *(const float4*)(
        x + ((((size_t)b * CIN + ci) * HW_ + y) * HW_) + xq * 4);
  }
#pragma unroll
  for (int j = 0; j < 4; ++j) {
    const int xx = xq * 4 + j;
    u16 oc[8];
#pragma unroll
    for (int k = 0; k < 8; ++k) oc[k] = f2bf(v[k][j]);
    u16* dst = xh + ((((size_t)b * PW + (y + 1)) * PW + (xx + 1)) << 9)
                  + i0 + c8 * 8;
    *(uint4*)dst = *(uint4*)oc;
  }
}

// ---------------------------------------------------------------------------
// Kernel 3a: demod sigma.  One block per o; w row staged float4-coalesced
// into LDS; per-thread q for 2 channels kept in registers; 16-batch dot with
// one barrier.  sig[b][o] parked in d_out scratch (conv overwrites later).
__global__ __launch_bounds__(256) void sigma_kernel(const float* __restrict__ w,
                                                    const float* __restrict__ s,
                                                    float* __restrict__ sig) {
  __shared__ float row[CIN * 9];       // 18,432 B
  __shared__ float part[16][4];

  const int o   = blockIdx.x;
  const int tid = threadIdx.x;
  const int wv  = tid >> 6;
  const int lane = tid & 63;
  const float* wrow = w + (size_t)o * (CIN * 9);

  // stage row: 1152 float4
#pragma unroll
  for (int it = 0; it < 5; ++it) {
    const int c = it * 256 + tid;
    if (c < 1152) *(float4*)&row[c * 4] = *(const float4*)(wrow + c * 4);
  }
  __syncthreads();

  float q0 = 0.f, q1 = 0.f;
#pragma unroll
  for (int tt = 0; tt < 9; ++tt) {
    const float a = row[(2 * tid) * 9 + tt];
    const float c = row[(2 * tid + 1) * 9 + tt];
    q0 += a * a; q1 += c * c;
  }

  const float C_EQ = 1.4731391e-2f;                 // 1/sqrt(512*9)
#pragma unroll
  for (int b = 0; b < 16; ++b) {
    const float2 sv = *(const float2*)(s + (size_t)b * CIN + 2 * tid);
    float a = q0 * sv.x * sv.x + q1 * sv.y * sv.y;
#pragma unroll
    for (int off = 32; off > 0; off >>= 1) a += __shfl_xor(a, off, 64);
    if (lane == 0) part[b][wv] = a;
  }
  __syncthreads();
  if (tid < 16) {
    const float tot = part[tid][0] + part[tid][1] + part[tid][2] + part[tid][3];
    sig[(size_t)tid * COUT + o] = rsqrtf(tot * (C_EQ * C_EQ) + 1e-8f);
  }
}

// ---------------------------------------------------------------------------
// Kernel 3b: scale + layout weights.  Block = (b, icc, o-half of 32).
// Transposed LDS wld[il*9+tap][o_local] (+1 pad): float4-coalesced loads,
// conflict-free (<=2-way) reads, 64 B-granular uint2 stores.
__global__ __launch_bounds__(256) void scale_weights(const float* __restrict__ w,
                                                     const float* __restrict__ s,
                                                     const float* __restrict__ sig,
                                                     u16* __restrict__ wA) {
  __shared__ float wld[288][33];     // 38,016 B
  __shared__ float s2[32];
  __shared__ float si[32];

  const int tid = threadIdx.x;
  // XCD swizzle: 4096 = 8 XCDs x 512.  XCD k owns o-rows [64k, 64k+64):
  // its w slice (1.18 MB) stays L2-resident across 512 blocks.
  const int k   = blockIdx.x & 7;
  const int j   = blockIdx.x >> 3;   // 0..511
  const int oh  = (k << 1) | (j & 1);
  const int icc = (j >> 1) & 15;
  const int b   = j >> 5;            // 0..15
  const int o0  = oh << 5;           // 32 outputs per block

  // load slab: 32 o x 288 floats, float4-coalesced, scatter-write transposed
#pragma unroll
  for (int it = 0; it < 9; ++it) {
    const int c   = it * 256 + tid;      // 0..2303
    const int ol  = c / 72;
    const int col = c - ol * 72;
    const float4 v = *(const float4*)(
        w + (size_t)(o0 + ol) * (CIN * 9) + icc * 288 + col * 4);
#pragma unroll
    for (int j2 = 0; j2 < 4; ++j2) wld[col * 4 + j2][ol] = v[j2];
  }
  if (tid < 32)      s2[tid] = 1.4731391e-2f * s[(size_t)b * CIN + icc * 32 + tid];
  else if (tid < 64) si[tid - 32] = sig[(size_t)b * COUT + o0 + (tid - 32)];
  __syncthreads();

  // emit: thread (ol = tid>>3, g4 = tid&7) writes 4 ch (8 B); 8 lanes = 64 B
  const int ol = tid >> 3;
  const int g4 = tid & 7;
  const float sg = si[ol];
  u16* base = wA + (size_t)b * (16 * 9 * COUT * 32);
#pragma unroll
  for (int tap = 0; tap < 9; ++tap) {
    u16 oc[4];
#pragma unroll
    for (int kk = 0; kk < 4; ++kk) {
      const int ich = g4 * 4 + kk;
      oc[kk] = f2bf(wld[ich * 9 + tap][ol] * s2[ich] * sg);
    }
    *(uint2*)(base + (((size_t)(icc * 9 + tap) * COUT) + o0 + ol) * 32 + g4 * 4)
        = *(uint2*)oc;
  }
}

// ---------------------------------------------------------------------------
// Kernel 4: implicit-GEMM conv, counted-vmcnt pipeline (T4).  UNCHANGED from
// round 3 (verified): 243 us, MfmaUtil 59.5%.
#define AS_ELEMS (128 * 32)            // 4096 u16 per A buffer (8 KB)
#define BROWS    (6 * 66)              // 396 rows per B buffer
#define BS_ELEMS (BROWS * 32)          // 12672 u16 per B buffer (25.3 KB)

__device__ __forceinline__ void stage_A(const u16* __restrict__ wb,
                                        u16* dst, int phase, int o0, int tid) {
  const u16* asrc = wb + ((size_t)phase * COUT + o0) * 32;
#pragma unroll
  for (int t = 0; t < 2; ++t) {
    const int id   = t * 256 + tid;
    const int row  = id >> 2;
    const int slot = (id & 3) ^ (row & 3);
    async16(asrc + row * 32 + slot * 8, dst + id * 8);
  }
}

__device__ __forceinline__ void stage_B_slice(const u16* __restrict__ xb,
                                              u16* dst, int ic, int y0,
                                              int tid, int slice) {
  if (tid < 198) {
    const int id   = slice * 198 + tid;
    const int row  = id >> 2;                  // rr*66+cc pixel in window
    const int slot = (id & 3) ^ (row & 3);
    async16(xb + ((size_t)y0 * PW + row) * CIN + ic * 32 + slot * 8,
            dst + id * 8);
  }
}

__global__ __launch_bounds__(256, 2) void modconv_mfma(const u16* __restrict__ xh,
                                                       const u16* __restrict__ wA,
                                                       const float* __restrict__ bias,
                                                       float* __restrict__ out) {
  __shared__ u16 As[3 * AS_ELEMS];     // 24 KB   [buf][o_local][ch]
  __shared__ u16 Bs[2 * BS_ELEMS];     // 50.7 KB [buf][row][ch]

  const int tid  = threadIdx.x;
  const int lane = tid & 63;
  const int wv   = tid >> 6;
  const int l15  = lane & 15;
  const int q    = lane >> 4;
  const int sw15 = l15 & 3;

  const int lin     = blockIdx.x;
  const int logical = ((lin & 7) << 7) + (lin >> 3);
  const int yt = logical & 15;
  const int ot = (logical >> 4) & 3;
  const int b  = logical >> 6;
  const int y0 = yt << 2;
  const int o0 = ot << 7;

  const u16* xb = xh + (size_t)b * (PW * PW * CIN);
  const u16* wb = wA + (size_t)b * (16 * 9 * COUT * 32);

  f32x4 acc[8][4];
#pragma unroll
  for (int mi = 0; mi < 8; ++mi)
#pragma unroll
    for (int cg = 0; cg < 4; ++cg) acc[mi][cg] = (f32x4){0.f, 0.f, 0.f, 0.f};

#pragma unroll
  for (int sl = 0; sl < 8; ++sl) stage_B_slice(xb, Bs, 0, y0, tid, sl);
  stage_A(wb, As, 0, o0, tid);
  stage_A(wb, As + AS_ELEMS, 1, o0, tid);

  for (int ic = 0; ic < 15; ++ic) {
    const int bOff = (ic & 1) * BS_ELEMS;
    const int bNxt = BS_ELEMS - bOff;
#pragma unroll
    for (int tap = 0; tap < 9; ++tap) {
      if (tap == 0) { WAITV(2); } else { WAITV(3); }
      __builtin_amdgcn_s_barrier();
      __builtin_amdgcn_sched_barrier(0);

      const int ky = tap / 3, kx = tap % 3;
      const int aCur = (tap % 3) * AS_ELEMS;
      const int aDst = ((tap + 2) % 3) * AS_ELEMS;
      const int rbbase = (wv + ky) * 66 + kx;

      bf16x8 bfr[4];
#pragma unroll
      for (int cg = 0; cg < 4; ++cg) {
        const int rb = rbbase + cg * 16 + l15;
        bfr[cg] = *(const bf16x8*)
          &Bs[bOff + (rb << 5) + ((q ^ (rb & 3)) << 3)];
      }

      stage_A(wb, As + aDst, ic * 9 + tap + 2, o0, tid);
      if (tap < 8) stage_B_slice(xb, Bs + bNxt, ic + 1, y0, tid, tap);

      __builtin_amdgcn_s_setprio(1);
#pragma unroll
      for (int mi = 0; mi < 8; ++mi) {
        const int ra = (mi << 4) + l15;
        const bf16x8 af = *(const bf16x8*)
          &As[aCur + (ra << 5) + ((q ^ sw15) << 3)];
#pragma unroll
        for (int cg = 0; cg < 4; ++cg)
          acc[mi][cg] = __builtin_amdgcn_mfma_f32_16x16x32_bf16(
              af, bfr[cg], acc[mi][cg], 0, 0, 0);
      }
      __builtin_amdgcn_s_setprio(0);
    }
  }

  {
    const int bOff = BS_ELEMS;
#pragma unroll
    for (int tap = 0; tap < 9; ++tap) {
      if (tap < 8) { WAITV(2); } else { WAITV(0); }
      __builtin_amdgcn_s_barrier();
      __builtin_amdgcn_sched_barrier(0);

      const int ky = tap / 3, kx = tap % 3;
      const int aCur = (tap % 3) * AS_ELEMS;
      const int rbbase = (wv + ky) * 66 + kx;

      bf16x8 bfr[4];
#pragma unroll
      for (int cg = 0; cg < 4; ++cg) {
        const int rb = rbbase + cg * 16 + l15;
        bfr[cg] = *(const bf16x8*)
          &Bs[bOff + (rb << 5) + ((q ^ (rb & 3)) << 3)];
      }

      if (tap <= 6)
        stage_A(wb, As + ((tap + 2) % 3) * AS_ELEMS, 135 + tap + 2, o0, tid);

      __builtin_amdgcn_s_setprio(1);
#pragma unroll
      for (int mi = 0; mi < 8; ++mi) {
        const int ra = (mi << 4) + l15;
        const bf16x8 af = *(const bf16x8*)
          &As[aCur + (ra << 5) + ((q ^ sw15) << 3)];
#pragma unroll
        for (int cg = 0; cg < 4; ++cg)
          acc[mi][cg] = __builtin_amdgcn_mfma_f32_16x16x32_bf16(
              af, bfr[cg], acc[mi][cg], 0, 0, 0);
      }
      __builtin_amdgcn_s_setprio(0);
    }
  }

  const int y = y0 + wv;
#pragma unroll
  for (int mi = 0; mi < 8; ++mi) {
#pragma unroll
    for (int rg = 0; rg < 4; ++rg) {
      const int o = o0 + (mi << 4) + (q << 2) + rg;
      const float bv = bias[o];
      const size_t base = (((size_t)b * COUT + o) * HW_ + y) * HW_;
#pragma unroll
      for (int cg = 0; cg < 4; ++cg)
        out[base + (cg << 4) + l15] = acc[mi][cg][rg] + bv;
    }
  }
}

// ---------------------------------------------------------------------------
extern "C" void kernel_launch(void* const* d_in, const int* in_sizes, int n_in,
                              void* d_out, int out_size, void* d_ws, size_t ws_size,
                              hipStream_t stream) {
  const float* x    = (const float*)d_in[0];   // [16][512][64][64] fp32
  const float* s    = (const float*)d_in[1];   // [16][512] fp32
  const float* w    = (const float*)d_in[2];   // [512][512][3][3] fp32
  const float* bias = (const float*)d_in[3];   // [512] fp32
  float* out = (float*)d_out;                  // [16][512][64][64] fp32

  u16* xh = (u16*)d_ws;                        // padded NHWC bf16 input
  u16* wA = xh + XH_ELEMS;                     // modulated bf16 weights
  float* sig = (float*)d_out;                  // 32 KB scratch, conv overwrites

  zero_border<<<(B_ * 260 * 64 + 255) / 256, 256, 0, stream>>>(xh);
  transpose_x<<<dim3(8, 32, 16), 256, 0, stream>>>(x, xh);
  sigma_kernel<<<512, 256, 0, stream>>>(w, s, sig);
  scale_weights<<<4096, 256, 0, stream>>>(w, s, sig, wA);
  modconv_mfma<<<1024, 256, 0, stream>>>(xh, wA, bias, out);
}

// Round 5
// 457.859 us; speedup vs baseline: 1.9975x; 1.0423x over previous
//
#include <hip/hip_runtime.h>
#include <cstdint>

typedef unsigned short u16;
typedef __bf16 bf16x8 __attribute__((ext_vector_type(8)));
typedef float f32x4 __attribute__((ext_vector_type(4)));

// Problem constants
#define B_    16
#define CIN   512
#define COUT  512
#define HW_   64
#define PW    66            // padded width/height
#define XH_ELEMS  ((size_t)B_*PW*PW*CIN)             // 35,684,352 u16 (71.4 MB)
#define WBF_ELEMS ((size_t)16*9*COUT*32)             //  2,359,296 u16 (4.7 MB)

#define WAITV(N) asm volatile("s_waitcnt vmcnt(" #N ")" ::: "memory")

__device__ __forceinline__ u16 f2bf(float f) {
  union { float f; unsigned int u; } c; c.f = f;
  unsigned int u = c.u + 0x7fffu + ((c.u >> 16) & 1u);   // RNE
  return (u16)(u >> 16);
}

// async global->LDS, 16B per lane; dest must be wave-uniform-base + lane*16
__device__ __forceinline__ void async16(const void* g, void* l) {
  __builtin_amdgcn_global_load_lds(
      (__attribute__((address_space(1))) unsigned int*)(uintptr_t)g,
      (__attribute__((address_space(3))) unsigned int*)(uintptr_t)l,
      16, 0, 0);
}

// ---------------------------------------------------------------------------
// Kernel 1: zero the padding border of xh[b][66][66][512]
__global__ __launch_bounds__(256) void zero_border(u16* __restrict__ xh) {
  int g = blockIdx.x * 256 + threadIdx.x;
  if (g >= B_ * 260 * 64) return;
  int c8 = g & 63;
  int t  = g >> 6;             // 0 .. 16*260-1
  int b  = t / 260;
  int p  = t - b * 260;
  int rp, cp;
  if (p < 66)       { rp = 0;      cp = p; }
  else if (p < 132) { rp = 65;     cp = p - 66; }
  else {
    int q = p - 132;           // 0..127
    if (q < 64) { rp = q + 1;  cp = 0; }
    else        { rp = q - 63; cp = 65; }
  }
  u16* dst = xh + ((((size_t)b * PW + rp) * PW + cp) << 9) + (c8 << 3);
  *(uint4*)dst = make_uint4(0u, 0u, 0u, 0u);
}

// ---------------------------------------------------------------------------
// Kernel 2: fp32 NCHW -> bf16 padded NHWC, FUSING the modulation scale:
// xh[b][y+1][x+1][i] = bf16( x[b][i][y][x] * C_EQ * s[b][i] ).
// Zero-LDS register transpose (round-4 structure, verified ~BW-floor).
__global__ __launch_bounds__(256) void transpose_x(const float* __restrict__ x,
                                                   const float* __restrict__ s,
                                                   u16* __restrict__ xh) {
  const int t   = threadIdx.x;
  const int c8  = t & 7;             // 8-channel group
  const int xq  = (t >> 3) & 15;     // x quad
  const int y01 = t >> 7;            // row within pair
  const int i0  = blockIdx.x * 64;
  const int y   = blockIdx.y * 2 + y01;
  const int b   = blockIdx.z;

  const float C_EQ = 1.4731391e-2f;                 // 1/sqrt(512*9)
  const float4 sA = *(const float4*)(s + (size_t)b * CIN + i0 + c8 * 8);
  const float4 sB = *(const float4*)(s + (size_t)b * CIN + i0 + c8 * 8 + 4);
  float cs[8] = {C_EQ * sA.x, C_EQ * sA.y, C_EQ * sA.z, C_EQ * sA.w,
                 C_EQ * sB.x, C_EQ * sB.y, C_EQ * sB.z, C_EQ * sB.w};

  float4 v[8];
#pragma unroll
  for (int k = 0; k < 8; ++k) {
    const int ci = i0 + c8 * 8 + k;
    v[k] = *(const float4*)(
        x + ((((size_t)b * CIN + ci) * HW_ + y) * HW_) + xq * 4);
  }
#pragma unroll
  for (int j = 0; j < 4; ++j) {
    const int xx = xq * 4 + j;
    u16 oc[8];
#pragma unroll
    for (int k = 0; k < 8; ++k) oc[k] = f2bf(v[k][j] * cs[k]);
    u16* dst = xh + ((((size_t)b * PW + (y + 1)) * PW + (xx + 1)) << 9)
                  + i0 + c8 * 8;
    *(uint4*)dst = *(uint4*)oc;
  }
}

// ---------------------------------------------------------------------------
// Kernel 3a: demod sigma.  One block per o; w row staged float4-coalesced
// into LDS; per-thread q for 2 channels in registers; 16-batch dot.
// sig[b][o] written to workspace scratch (read by conv epilogue).
__global__ __launch_bounds__(256) void sigma_kernel(const float* __restrict__ w,
                                                    const float* __restrict__ s,
                                                    float* __restrict__ sig) {
  __shared__ float row[CIN * 9];       // 18,432 B
  __shared__ float part[16][4];

  const int o   = blockIdx.x;
  const int tid = threadIdx.x;
  const int wv  = tid >> 6;
  const int lane = tid & 63;
  const float* wrow = w + (size_t)o * (CIN * 9);

#pragma unroll
  for (int it = 0; it < 5; ++it) {
    const int c = it * 256 + tid;
    if (c < 1152) *(float4*)&row[c * 4] = *(const float4*)(wrow + c * 4);
  }
  __syncthreads();

  float q0 = 0.f, q1 = 0.f;
#pragma unroll
  for (int tt = 0; tt < 9; ++tt) {
    const float a = row[(2 * tid) * 9 + tt];
    const float c = row[(2 * tid + 1) * 9 + tt];
    q0 += a * a; q1 += c * c;
  }

  const float C_EQ = 1.4731391e-2f;                 // 1/sqrt(512*9)
#pragma unroll
  for (int b = 0; b < 16; ++b) {
    const float2 sv = *(const float2*)(s + (size_t)b * CIN + 2 * tid);
    float a = q0 * sv.x * sv.x + q1 * sv.y * sv.y;
#pragma unroll
    for (int off = 32; off > 0; off >>= 1) a += __shfl_xor(a, off, 64);
    if (lane == 0) part[b][wv] = a;
  }
  __syncthreads();
  if (tid < 16) {
    const float tot = part[tid][0] + part[tid][1] + part[tid][2] + part[tid][3];
    sig[(size_t)tid * COUT + o] = rsqrtf(tot * (C_EQ * C_EQ) + 1e-8f);
  }
}

// ---------------------------------------------------------------------------
// Kernel 3b: raw-weight layout transform (batch-independent!).
// wbf[icc][tap][o][ich] = bf16(w[o][icc*32+ich][tap]).  4.7 MB, written once,
// L2/L3-resident for the conv.  Block = (icc, o-half of 32); 256 blocks.
__global__ __launch_bounds__(256) void wlayout(const float* __restrict__ w,
                                               u16* __restrict__ wbf) {
  __shared__ float wld[288][33];     // 38,016 B, transposed slab

  const int tid = threadIdx.x;
  const int icc = blockIdx.x & 15;
  const int oh  = blockIdx.x >> 4;   // 0..15
  const int o0  = oh << 5;           // 32 outputs per block

  // load slab: 32 o x 288 floats, float4-coalesced, scatter-write transposed
#pragma unroll
  for (int it = 0; it < 9; ++it) {
    const int c   = it * 256 + tid;      // 0..2303
    const int ol  = c / 72;
    const int col = c - ol * 72;
    const float4 v = *(const float4*)(
        w + (size_t)(o0 + ol) * (CIN * 9) + icc * 288 + col * 4);
#pragma unroll
    for (int j2 = 0; j2 < 4; ++j2) wld[col * 4 + j2][ol] = v[j2];
  }
  __syncthreads();

  // emit: thread (ol = tid>>3, g4 = tid&7) writes 4 ch (8 B); conflict-free
  const int ol = tid >> 3;
  const int g4 = tid & 7;
#pragma unroll
  for (int tap = 0; tap < 9; ++tap) {
    u16 oc[4];
#pragma unroll
    for (int kk = 0; kk < 4; ++kk)
      oc[kk] = f2bf(wld[(g4 * 4 + kk) * 9 + tap][ol]);
    *(uint2*)(wbf + (((size_t)(icc * 9 + tap) * COUT) + o0 + ol) * 32 + g4 * 4)
        = *(uint2*)oc;
  }
}

// ---------------------------------------------------------------------------
// Kernel 4: implicit-GEMM conv, counted-vmcnt pipeline (T4).  Identical to
// round-3/4 (verified 243-244 us, MfmaUtil 59%) except: A-operand is the
// SHARED raw-weight tensor wbf (no per-b offset), and the epilogue applies
// sig[b][o] before bias (demodulation factored out of the weights).
#define AS_ELEMS (128 * 32)            // 4096 u16 per A buffer (8 KB)
#define BROWS    (6 * 66)              // 396 rows per B buffer
#define BS_ELEMS (BROWS * 32)          // 12672 u16 per B buffer (25.3 KB)

__device__ __forceinline__ void stage_A(const u16* __restrict__ wb,
                                        u16* dst, int phase, int o0, int tid) {
  const u16* asrc = wb + ((size_t)phase * COUT + o0) * 32;
#pragma unroll
  for (int t = 0; t < 2; ++t) {
    const int id   = t * 256 + tid;
    const int row  = id >> 2;
    const int slot = (id & 3) ^ (row & 3);
    async16(asrc + row * 32 + slot * 8, dst + id * 8);
  }
}

__device__ __forceinline__ void stage_B_slice(const u16* __restrict__ xb,
                                              u16* dst, int ic, int y0,
                                              int tid, int slice) {
  if (tid < 198) {
    const int id   = slice * 198 + tid;
    const int row  = id >> 2;                  // rr*66+cc pixel in window
    const int slot = (id & 3) ^ (row & 3);
    async16(xb + ((size_t)y0 * PW + row) * CIN + ic * 32 + slot * 8,
            dst + id * 8);
  }
}

__global__ __launch_bounds__(256, 2) void modconv_mfma(const u16* __restrict__ xh,
                                                       const u16* __restrict__ wbf,
                                                       const float* __restrict__ sig,
                                                       const float* __restrict__ bias,
                                                       float* __restrict__ out) {
  __shared__ u16 As[3 * AS_ELEMS];     // 24 KB   [buf][o_local][ch]
  __shared__ u16 Bs[2 * BS_ELEMS];     // 50.7 KB [buf][row][ch]

  const int tid  = threadIdx.x;
  const int lane = tid & 63;
  const int wv   = tid >> 6;
  const int l15  = lane & 15;
  const int q    = lane >> 4;
  const int sw15 = l15 & 3;

  const int lin     = blockIdx.x;
  const int logical = ((lin & 7) << 7) + (lin >> 3);
  const int yt = logical & 15;
  const int ot = (logical >> 4) & 3;
  const int b  = logical >> 6;
  const int y0 = yt << 2;
  const int o0 = ot << 7;

  const u16* xb = xh + (size_t)b * (PW * PW * CIN);
  const u16* wb = wbf;                 // shared across batches

  f32x4 acc[8][4];
#pragma unroll
  for (int mi = 0; mi < 8; ++mi)
#pragma unroll
    for (int cg = 0; cg < 4; ++cg) acc[mi][cg] = (f32x4){0.f, 0.f, 0.f, 0.f};

#pragma unroll
  for (int sl = 0; sl < 8; ++sl) stage_B_slice(xb, Bs, 0, y0, tid, sl);
  stage_A(wb, As, 0, o0, tid);
  stage_A(wb, As + AS_ELEMS, 1, o0, tid);

  for (int ic = 0; ic < 15; ++ic) {
    const int bOff = (ic & 1) * BS_ELEMS;
    const int bNxt = BS_ELEMS - bOff;
#pragma unroll
    for (int tap = 0; tap < 9; ++tap) {
      if (tap == 0) { WAITV(2); } else { WAITV(3); }
      __builtin_amdgcn_s_barrier();
      __builtin_amdgcn_sched_barrier(0);

      const int ky = tap / 3, kx = tap % 3;
      const int aCur = (tap % 3) * AS_ELEMS;
      const int aDst = ((tap + 2) % 3) * AS_ELEMS;
      const int rbbase = (wv + ky) * 66 + kx;

      bf16x8 bfr[4];
#pragma unroll
      for (int cg = 0; cg < 4; ++cg) {
        const int rb = rbbase + cg * 16 + l15;
        bfr[cg] = *(const bf16x8*)
          &Bs[bOff + (rb << 5) + ((q ^ (rb & 3)) << 3)];
      }

      stage_A(wb, As + aDst, ic * 9 + tap + 2, o0, tid);
      if (tap < 8) stage_B_slice(xb, Bs + bNxt, ic + 1, y0, tid, tap);

      __builtin_amdgcn_s_setprio(1);
#pragma unroll
      for (int mi = 0; mi < 8; ++mi) {
        const int ra = (mi << 4) + l15;
        const bf16x8 af = *(const bf16x8*)
          &As[aCur + (ra << 5) + ((q ^ sw15) << 3)];
#pragma unroll
        for (int cg = 0; cg < 4; ++cg)
          acc[mi][cg] = __builtin_amdgcn_mfma_f32_16x16x32_bf16(
              af, bfr[cg], acc[mi][cg], 0, 0, 0);
      }
      __builtin_amdgcn_s_setprio(0);
    }
  }

  {
    const int bOff = BS_ELEMS;
#pragma unroll
    for (int tap = 0; tap < 9; ++tap) {
      if (tap < 8) { WAITV(2); } else { WAITV(0); }
      __builtin_amdgcn_s_barrier();
      __builtin_amdgcn_sched_barrier(0);

      const int ky = tap / 3, kx = tap % 3;
      const int aCur = (tap % 3) * AS_ELEMS;
      const int rbbase = (wv + ky) * 66 + kx;

      bf16x8 bfr[4];
#pragma unroll
      for (int cg = 0; cg < 4; ++cg) {
        const int rb = rbbase + cg * 16 + l15;
        bfr[cg] = *(const bf16x8*)
          &Bs[bOff + (rb << 5) + ((q ^ (rb & 3)) << 3)];
      }

      if (tap <= 6)
        stage_A(wb, As + ((tap + 2) % 3) * AS_ELEMS, 135 + tap + 2, o0, tid);

      __builtin_amdgcn_s_setprio(1);
#pragma unroll
      for (int mi = 0; mi < 8; ++mi) {
        const int ra = (mi << 4) + l15;
        const bf16x8 af = *(const bf16x8*)
          &As[aCur + (ra << 5) + ((q ^ sw15) << 3)];
#pragma unroll
        for (int cg = 0; cg < 4; ++cg)
          acc[mi][cg] = __builtin_amdgcn_mfma_f32_16x16x32_bf16(
              af, bfr[cg], acc[mi][cg], 0, 0, 0);
      }
      __builtin_amdgcn_s_setprio(0);
    }
  }

  // epilogue: out = sig[b][o] * acc + bias[o]
  const float* sigrow = sig + (size_t)b * COUT;
  const int y = y0 + wv;
#pragma unroll
  for (int mi = 0; mi < 8; ++mi) {
#pragma unroll
    for (int rg = 0; rg < 4; ++rg) {
      const int o = o0 + (mi << 4) + (q << 2) + rg;
      const float sgv = sigrow[o];
      const float bv  = bias[o];
      const size_t base = (((size_t)b * COUT + o) * HW_ + y) * HW_;
#pragma unroll
      for (int cg = 0; cg < 4; ++cg)
        out[base + (cg << 4) + l15] = acc[mi][cg][rg] * sgv + bv;
    }
  }
}

// ---------------------------------------------------------------------------
extern "C" void kernel_launch(void* const* d_in, const int* in_sizes, int n_in,
                              void* d_out, int out_size, void* d_ws, size_t ws_size,
                              hipStream_t stream) {
  const float* x    = (const float*)d_in[0];   // [16][512][64][64] fp32
  const float* s    = (const float*)d_in[1];   // [16][512] fp32
  const float* w    = (const float*)d_in[2];   // [512][512][3][3] fp32
  const float* bias = (const float*)d_in[3];   // [512] fp32
  float* out = (float*)d_out;                  // [16][512][64][64] fp32

  u16* xh    = (u16*)d_ws;                     // padded NHWC bf16 (x*C*s)
  u16* wbf   = xh + XH_ELEMS;                  // raw bf16 weights, MFMA layout
  float* sig = (float*)(wbf + WBF_ELEMS);      // [16][512] demod scales

  zero_border<<<(B_ * 260 * 64 + 255) / 256, 256, 0, stream>>>(xh);
  transpose_x<<<dim3(8, 32, 16), 256, 0, stream>>>(x, s, xh);
  sigma_kernel<<<512, 256, 0, stream>>>(w, s, sig);
  wlayout<<<256, 256, 0, stream>>>(w, wbf);
  modconv_mfma<<<1024, 256, 0, stream>>>(xh, wbf, sig, bias, out);
}